// Round 11
// baseline (379.175 us; speedup 1.0000x reference)
//
#include <hip/hip_runtime.h>
#include <stdint.h>

#define NN 50000
#define NE 800000
#define DIM 256

// agg slice params: 4 channel-slices of 64 ch (128B rows = full cache line per gather).
#define NSLICE 4
#define SCH 64
#define NPB 64      // dst nodes per block (8 waves... 4 waves x 16? -> 256 thr / 8 lanes = 32 grp) *2 via NPB
#define ECH 2048    // staged edges per LDS chunk (8 KB)

// gemm: 64-row tiles
#define GR 64
#define GB ((NN + GR - 1) / GR)   // 782

// scan: 49 chunks x 1024 nodes
#define SCB 49

typedef __bf16 bf16x8 __attribute__((ext_vector_type(8)));
typedef float f32x4 __attribute__((ext_vector_type(4)));
typedef float f32x2 __attribute__((ext_vector_type(2)));
typedef unsigned u32x4 __attribute__((ext_vector_type(4)));
typedef int i32x4 __attribute__((ext_vector_type(4)));

__device__ __forceinline__ unsigned short f2bf(float f) {
  union { float f; unsigned u; } v; v.f = f;
  unsigned r = v.u + 0x7fffu + ((v.u >> 16) & 1u);
  return (unsigned short)(r >> 16);
}

// async global->LDS 16B (wave-uniform LDS base + lane*16; global source per-lane)
__device__ __forceinline__ void gload_lds16(const void* g, void* l) {
  __builtin_amdgcn_global_load_lds(
      (const __attribute__((address_space(1))) unsigned*)g,
      (__attribute__((address_space(3))) unsigned*)l, 16, 0, 0);
}

// ---------------- zero counters + pooled output ----------------
__global__ __launch_bounds__(256) void zero_kernel(int* __restrict__ cnt, float* __restrict__ hg) {
  int i = blockIdx.x * 256 + threadIdx.x;
  if (i < 2 * NN) cnt[i] = 0;
  if (i < 512) hg[i] = 0.f;
}

// ---------------- degrees via global atomics (50K addresses, ~16 collisions avg) ----------------
__global__ __launch_bounds__(256) void deg_kernel(const int* __restrict__ src,
                                                  const int* __restrict__ dst,
                                                  int* __restrict__ cnt) {
  int t = blockIdx.x * 256 + threadIdx.x;
  if (t < NE / 4) {
    i32x4 s4 = *(const i32x4*)(src + t * 4);
    i32x4 d4 = *(const i32x4*)(dst + t * 4);
    atomicAdd(&cnt[s4.x], 1);
    atomicAdd(&cnt[s4.y], 1);
    atomicAdd(&cnt[s4.z], 1);
    atomicAdd(&cnt[s4.w], 1);
    atomicAdd(&cnt[NN + d4.x], 1);
    atomicAdd(&cnt[NN + d4.y], 1);
    atomicAdd(&cnt[NN + d4.z], 1);
    atomicAdd(&cnt[NN + d4.w], 1);
  }
}

// ---------------- norms + scan chunk partial sums ----------------
__global__ __launch_bounds__(256) void norm_kernel(const int* __restrict__ cnt,
                                                   float* __restrict__ norm_s,
                                                   float* __restrict__ norm_d,
                                                   int* __restrict__ csum) {
  __shared__ int ws[4];
  int tid = threadIdx.x;
  int i0 = blockIdx.x * 1024 + tid * 4;
  int dsum = 0;
#pragma unroll
  for (int j = 0; j < 4; ++j) {
    int i = i0 + j;
    if (i < NN) {
      int s = cnt[i], d = cnt[NN + i];
      norm_s[i] = rsqrtf(fmaxf((float)s, 1.0f));
      norm_d[i] = rsqrtf(fmaxf((float)d, 1.0f));
      dsum += d;
    }
  }
  int lane = tid & 63, wave = tid >> 6;
#pragma unroll
  for (int off = 32; off; off >>= 1) dsum += __shfl_down(dsum, off, 64);
  if (lane == 0) ws[wave] = dsum;
  __syncthreads();
  if (tid == 0) csum[blockIdx.x] = ws[0] + ws[1] + ws[2] + ws[3];
}

// ---------------- scan write: inline 49-entry chunk prefix + node prefix; also cursor copy ----------------
__global__ __launch_bounds__(256) void scan_write_kernel(const int* __restrict__ cnt,
                                                         const int* __restrict__ csum,
                                                         int* __restrict__ row_ptr,
                                                         int* __restrict__ cur) {
  __shared__ int wsum[4];
  int tid = threadIdx.x, lane = tid & 63, wave = tid >> 6;
  const int* in_cnt = cnt + NN;
  // chunk offsets: every thread scans csum[0..48] in-register
  int cv = (lane < SCB) ? csum[lane] : 0;
  int cincl = cv;
#pragma unroll
  for (int off = 1; off < 64; off <<= 1) {
    int t = __shfl_up(cincl, off, 64);
    if (lane >= off) cincl += t;
  }
  int myoff = __shfl(cincl, blockIdx.x, 64) - __shfl(cv, blockIdx.x, 64);
  int total = __shfl(cincl, SCB - 1, 64);
  if (blockIdx.x == 0 && tid == 0) row_ptr[NN] = total;

  int i0 = blockIdx.x * 1024 + tid * 4;
  int v[4];
#pragma unroll
  for (int j = 0; j < 4; ++j) {
    int i = i0 + j;
    v[j] = (i < NN) ? in_cnt[i] : 0;
  }
  int tsum = v[0] + v[1] + v[2] + v[3];
  int incl = tsum;
#pragma unroll
  for (int off = 1; off < 64; off <<= 1) {
    int t = __shfl_up(incl, off, 64);
    if (lane >= off) incl += t;
  }
  if (lane == 63) wsum[wave] = incl;
  __syncthreads();
  int woff = 0;
  for (int w = 0; w < wave; ++w) woff += wsum[w];
  int run = myoff + woff + (incl - tsum);
#pragma unroll
  for (int j = 0; j < 4; ++j) {
    int i = i0 + j;
    if (i < NN) { row_ptr[i] = run; cur[i] = run; }
    run += v[j];
  }
}

// ---------------- CSR fill via atomic cursor (order within row arbitrary; sums unaffected) ----------------
// Stores PRE-SCALED byte offsets: colx[..] = src*128 (128B slice-row byte offset).
__global__ __launch_bounds__(256) void fill_kernel(const int* __restrict__ src,
                                                   const int* __restrict__ dst,
                                                   int* __restrict__ cur,
                                                   int* __restrict__ colx) {
  int t = blockIdx.x * 256 + threadIdx.x;
  if (t < NE / 4) {
    i32x4 s4 = *(const i32x4*)(src + t * 4);
    i32x4 d4 = *(const i32x4*)(dst + t * 4);
    int p0 = atomicAdd(&cur[d4.x], 1);
    colx[p0] = s4.x << 7;
    int p1 = atomicAdd(&cur[d4.y], 1);
    colx[p1] = s4.y << 7;
    int p2 = atomicAdd(&cur[d4.z], 1);
    colx[p2] = s4.z << 7;
    int p3 = atomicAdd(&cur[d4.w], 1);
    colx[p3] = s4.w << 7;
  }
}

// ---------------- fused prep: cast feat (scaled by norm_s, SLICE-MAJOR 64ch) + swizzle W0/W1 ----------------
__device__ __forceinline__ void swizzleW_body(const float* __restrict__ W,
                                              unsigned short* __restrict__ Wb, int idx) {
  int lane = idx & 63;
  int blk = idx >> 6;
  int kc = blk & 7, nt = blk >> 3;
  int kbase = kc * 32 + (lane >> 4) * 8;
  int col = nt * 16 + (lane & 15);
  ushort4 o0, o1;
  o0.x = f2bf(W[(size_t)(kbase + 0) * DIM + col]);
  o0.y = f2bf(W[(size_t)(kbase + 1) * DIM + col]);
  o0.z = f2bf(W[(size_t)(kbase + 2) * DIM + col]);
  o0.w = f2bf(W[(size_t)(kbase + 3) * DIM + col]);
  o1.x = f2bf(W[(size_t)(kbase + 4) * DIM + col]);
  o1.y = f2bf(W[(size_t)(kbase + 5) * DIM + col]);
  o1.z = f2bf(W[(size_t)(kbase + 6) * DIM + col]);
  o1.w = f2bf(W[(size_t)(kbase + 7) * DIM + col]);
  ((ushort4*)Wb)[idx * 2 + 0] = o0;
  ((ushort4*)Wb)[idx * 2 + 1] = o1;
}

__global__ void prep_kernel(const float* __restrict__ feat, const float* __restrict__ norm_s,
                            unsigned short* __restrict__ featb,
                            const float* __restrict__ W0, unsigned short* __restrict__ Wb0,
                            const float* __restrict__ W1, unsigned short* __restrict__ Wb1) {
  int blk = blockIdx.x;
  if (blk < 12500) {
    int i = blk * 256 + threadIdx.x;  // float4 index over feat
    int node = i >> 6;
    int ch4 = i & 63;
    float s = norm_s[node];
    float4 v = ((const float4*)feat)[i];
    ushort4 o;
    o.x = f2bf(v.x * s); o.y = f2bf(v.y * s); o.z = f2bf(v.z * s); o.w = f2bf(v.w * s);
    int sl = ch4 >> 4;                // slice = ch/64
    int w4 = ch4 & 15;
    ((ushort4*)featb)[(size_t)sl * (NN * 16) + (size_t)node * 16 + w4] = o;
  } else if (blk < 12532) {
    swizzleW_body(W0, Wb0, (blk - 12500) * 256 + threadIdx.x);
  } else {
    swizzleW_body(W1, Wb1, (blk - 12532) * 256 + threadIdx.x);
  }
}

// ---------------- gather-aggregate, slice-major 128B rows + LDS-staged pre-scaled colx ----------------
// Latency x concurrency bound (r10 analysis): 16-deep unroll doubles per-wave
// outstanding loads; colx staging is CACHED (re-read once per slice pass, 4x) so it
// stops paying HBM latency; NPB=64 amortizes staging barriers over 2x edges.
// Output aggb is XOR-SWIZZLED: 16B chunk column p -> p ^ ((node&7)<<4) (see gemm).
__device__ __forceinline__ void acc_row(f32x2* a, u32x4 p) {
  f32x2 v0 = { __uint_as_float(p.x << 16), __uint_as_float(p.x & 0xffff0000u) };
  a[0] += v0;
  f32x2 v1 = { __uint_as_float(p.y << 16), __uint_as_float(p.y & 0xffff0000u) };
  a[1] += v1;
  f32x2 v2 = { __uint_as_float(p.z << 16), __uint_as_float(p.z & 0xffff0000u) };
  a[2] += v2;
  f32x2 v3 = { __uint_as_float(p.w << 16), __uint_as_float(p.w & 0xffff0000u) };
  a[3] += v3;
}

__global__ __launch_bounds__(256) void agg_kernel(const unsigned short* __restrict__ X,
                                                  unsigned short* __restrict__ agg,
                                                  const int* __restrict__ row_ptr,
                                                  const int* __restrict__ colx,
                                                  const float* __restrict__ norm_d) {
  __shared__ int ecol[ECH];
  const int s = blockIdx.x & (NSLICE - 1);
  const int nb = blockIdx.x >> 2;
  const int tid = threadIdx.x;
  const int grp = tid >> 3;                  // one dst node per 8-lane group (32 grp/256thr? -> NPB=64 needs 2 nodes/grp? no: 256/8=32; NPB=64 -> 2 passes)
  const int cl = tid & 7;                    // 16B sub-chunk of the 128B row

  const int nfirst = nb * NPB;
  const int nlast = (nfirst + NPB < NN) ? (nfirst + NPB) : NN;
  const int estart = row_ptr[nfirst];
  const int eend = row_ptr[nlast];

  const char* Xp = (const char*)(X + (size_t)s * (NN * SCH));
  const int lsub = cl * 16;

  // two nodes per group: grp handles nfirst+grp and nfirst+32+grp
  int nodes[2];
  nodes[0] = nfirst + grp;
  nodes[1] = nfirst + 32 + grp;

  f32x2 acc2[2][4];
#pragma unroll
  for (int q = 0; q < 2; ++q)
#pragma unroll
    for (int j = 0; j < 4; ++j) acc2[q][j] = (f32x2){0.f, 0.f};

  int e_[2], end_[2];
#pragma unroll
  for (int q = 0; q < 2; ++q) {
    if (nodes[q] < NN) { e_[q] = row_ptr[nodes[q]]; end_[q] = row_ptr[nodes[q] + 1]; }
    else { e_[q] = 0; end_[q] = 0; }
  }

  const int base0 = estart & ~3;
  for (int base = base0; base < eend; base += ECH) {
    const int lim = (base + ECH < eend) ? (base + ECH) : eend;
    __syncthreads();
    for (int k = base + tid * 4; k < lim; k += 1024) {
      i32x4 v = *(const i32x4*)(colx + k);
      *(i32x4*)&ecol[k - base] = v;
    }
    __syncthreads();
#pragma unroll
    for (int q = 0; q < 2; ++q) {
      int e = e_[q];
      const int hi = (end_[q] < lim) ? end_[q] : lim;
      f32x2* a = acc2[q];
      for (; e + 16 <= hi; e += 16) {
        int o_[16];
#pragma unroll
        for (int j = 0; j < 16; ++j) o_[j] = ecol[e - base + j];
        u32x4 r_[16];
#pragma unroll
        for (int j = 0; j < 16; ++j)
          r_[j] = *(const u32x4*)(Xp + (size_t)(unsigned)(o_[j] | lsub));
#pragma unroll
        for (int j = 0; j < 16; ++j) acc_row(a, r_[j]);
      }
      if (e + 8 <= hi) {
        int o_[8];
#pragma unroll
        for (int j = 0; j < 8; ++j) o_[j] = ecol[e - base + j];
        u32x4 r_[8];
#pragma unroll
        for (int j = 0; j < 8; ++j)
          r_[j] = *(const u32x4*)(Xp + (size_t)(unsigned)(o_[j] | lsub));
#pragma unroll
        for (int j = 0; j < 8; ++j) acc_row(a, r_[j]);
        e += 8;
      }
      if (e + 4 <= hi) {
        int o_[4];
#pragma unroll
        for (int j = 0; j < 4; ++j) o_[j] = ecol[e - base + j];
        u32x4 r_[4];
#pragma unroll
        for (int j = 0; j < 4; ++j)
          r_[j] = *(const u32x4*)(Xp + (size_t)(unsigned)(o_[j] | lsub));
#pragma unroll
        for (int j = 0; j < 4; ++j) acc_row(a, r_[j]);
        e += 4;
      }
      for (; e < hi; ++e) {
        int o0 = ecol[e - base];
        u32x4 r = *(const u32x4*)(Xp + (size_t)(unsigned)(o0 | lsub));
        acc_row(a, r);
      }
      e_[q] = e;
    }
  }

#pragma unroll
  for (int q = 0; q < 2; ++q) {
    int node = nodes[q];
    if (node < NN) {
      float nd = norm_d[node];
      f32x2* a = acc2[q];
      u32x4 o;
      o.x = (unsigned)f2bf(a[0].x * nd) | ((unsigned)f2bf(a[0].y * nd) << 16);
      o.y = (unsigned)f2bf(a[1].x * nd) | ((unsigned)f2bf(a[1].y * nd) << 16);
      o.z = (unsigned)f2bf(a[2].x * nd) | ((unsigned)f2bf(a[2].y * nd) << 16);
      o.w = (unsigned)f2bf(a[3].x * nd) | ((unsigned)f2bf(a[3].y * nd) << 16);
      // swizzled store: chunk col p ^ ((node&7)<<4); contiguous 128B per group
      unsigned pcol = (unsigned)(s * 128 + cl * 16) ^ (((unsigned)node & 7u) << 4);
      __builtin_nontemporal_store(o, (u32x4*)((char*)agg + (size_t)node * 512 + pcol));
    }
  }
}

// ---------------- MFMA GEMM (64-row tile): global_load_lds linear staging + XOR ds_read ----------------
// A (=aggb) is byte-swizzled by agg; staging is a pure linear 32KB copy via
// global_load_lds width=16; ds_read applies c ^= (row&7)<<4 to recover canonical chunks.
// Pooling: contention-free per-block column partials to hg_part.
// Exactly one of C (f32, canonical row-major) / Cb (bf16, canonical SLICE-MAJOR 64ch) non-null.
#define FROW 260     // f32 row stride for epilogue staging
__global__ __launch_bounds__(256) void gemm_mfma_kernel(const unsigned short* __restrict__ A,
                                                        const unsigned short* __restrict__ Wb,
                                                        const float* __restrict__ bias,
                                                        const float* __restrict__ prelu_a_ptr,
                                                        const float* __restrict__ norm_s,
                                                        float* __restrict__ C,
                                                        unsigned short* __restrict__ Cb,
                                                        float* __restrict__ hg_part) {
  __shared__ __attribute__((aligned(16))) char Asb[GR * 512];  // 32768 B, linear; reused as LF
  int tid = threadIdx.x;
  int r0 = blockIdx.x * GR;
  const char* Ab = (const char*)A;
#pragma unroll
  for (int p = 0; p < 8; ++p) {
    int off = p * 4096 + tid * 16;
    int row = off >> 9;
    int col = off & 511;
    int grow = r0 + row;
    if (grow > NN - 1) grow = NN - 1;  // clamp: OOB rows read row NN-1 (outputs masked)
    gload_lds16(Ab + (size_t)grow * 512 + col, Asb + off);
  }
  __syncthreads();

  int wave = tid >> 6, lane = tid & 63;
  int quad = lane >> 4, l16 = lane & 15;

  f32x4 acc[4][4];
#pragma unroll
  for (int mt = 0; mt < 4; ++mt)
#pragma unroll
    for (int nti = 0; nti < 4; ++nti)
      acc[mt][nti] = (f32x4){0.f, 0.f, 0.f, 0.f};

#pragma unroll
  for (int kc = 0; kc < 8; ++kc) {
    bf16x8 a[4], b[4];
#pragma unroll
    for (int mt = 0; mt < 4; ++mt) {
      int row = mt * 16 + l16;
      int c = (kc * 64 + quad * 16) ^ ((row & 7) << 4);
      a[mt] = *(const bf16x8*)(Asb + row * 512 + c);
    }
#pragma unroll
    for (int nti = 0; nti < 4; ++nti) {
      int nt = wave * 4 + nti;
      b[nti] = *(const bf16x8*)(Wb + ((size_t)(nt * 8 + kc) * 64 + lane) * 8);
    }
#pragma unroll
    for (int mt = 0; mt < 4; ++mt)
#pragma unroll
      for (int nti = 0; nti < 4; ++nti)
        acc[mt][nti] = __builtin_amdgcn_mfma_f32_16x16x32_bf16(a[mt], b[nti], acc[mt][nti], 0, 0, 0);
  }

  // bias + PReLU + column sums in registers (C-layout: col=l16, row=mt*16+quad*4+r)
  float pa = *prelu_a_ptr;
  float bv[4], cs[4];
#pragma unroll
  for (int nti = 0; nti < 4; ++nti) {
    bv[nti] = bias[wave * 64 + nti * 16 + l16];
    cs[nti] = 0.f;
  }
#pragma unroll
  for (int mt = 0; mt < 4; ++mt) {
#pragma unroll
    for (int nti = 0; nti < 4; ++nti) {
#pragma unroll
      for (int r = 0; r < 4; ++r) {
        int rowg = r0 + mt * 16 + quad * 4 + r;
        float x = acc[mt][nti][r] + bv[nti];
        x = (x >= 0.f) ? x : pa * x;
        acc[mt][nti][r] = x;
        if (rowg < NN) cs[nti] += x;
      }
    }
  }
#pragma unroll
  for (int nti = 0; nti < 4; ++nti) {
    cs[nti] += __shfl_xor(cs[nti], 16, 64);
    cs[nti] += __shfl_xor(cs[nti], 32, 64);
  }
  if (quad == 0) {
#pragma unroll
    for (int nti = 0; nti < 4; ++nti)
      hg_part[(size_t)blockIdx.x * 256 + wave * 64 + nti * 16 + l16] = cs[nti];
  }

  // coalesced store epilogue: stage 16-row chunks through LDS
  float* LF = (float*)Asb;  // [16][FROW] = 16640 B < 32768 B
#pragma unroll
  for (int chunk = 0; chunk < 4; ++chunk) {
    __syncthreads();
#pragma unroll
    for (int nti = 0; nti < 4; ++nti) {
      int colw = wave * 64 + nti * 16 + l16;
#pragma unroll
      for (int r = 0; r < 4; ++r)
        LF[(quad * 4 + r) * FROW + colw] = acc[chunk][nti][r];
    }
    __syncthreads();
    int rowbase = r0 + chunk * 16;
    if (C) {
#pragma unroll
      for (int s = 0; s < 4; ++s) {
        int g = s * 256 + tid;
        int row = g >> 6, cg = g & 63;
        int rowg = rowbase + row;
        if (rowg < NN) {
          float4 v = *(const float4*)&LF[row * FROW + cg * 4];
          *(float4*)(C + (size_t)rowg * DIM + cg * 4) = v;
        }
      }
    }
    if (Cb) {
#pragma unroll
      for (int s = 0; s < 2; ++s) {
        int g = s * 256 + tid;
        int row = g >> 5, cg = g & 31;    // cg: 8-channel group (0..31)
        int rowg = rowbase + row;
        if (rowg < NN) {
          float ns = norm_s[rowg];
          float4 v0 = *(const float4*)&LF[row * FROW + cg * 8];
          float4 v1 = *(const float4*)&LF[row * FROW + cg * 8 + 4];
          uint4 o;
          o.x = (unsigned)f2bf(v0.x * ns) | ((unsigned)f2bf(v0.y * ns) << 16);
          o.y = (unsigned)f2bf(v0.z * ns) | ((unsigned)f2bf(v0.w * ns) << 16);
          o.z = (unsigned)f2bf(v1.x * ns) | ((unsigned)f2bf(v1.y * ns) << 16);
          o.w = (unsigned)f2bf(v1.z * ns) | ((unsigned)f2bf(v1.w * ns) << 16);
          // canonical slice-major store: slice = cg>>3, 8ch-group within slice = cg&7
          unsigned short* outp = Cb + (size_t)(cg >> 3) * (NN * SCH)
                               + (size_t)rowg * SCH + (size_t)(cg & 7) * 8;
          *(uint4*)outp = o;
        }
      }
    }
  }
}

// ---------------- pooled-output reduction: hg[layer][c] = sum_b hg_part[layer][b][c] ----------------
__global__ __launch_bounds__(256) void hg_reduce_kernel(const float* __restrict__ hg_part,
                                                        float* __restrict__ hg) {
  const int layer = blockIdx.x >> 3;
  const int chunk = blockIdx.x & 7;
  const int c = threadIdx.x;
  const float* base = hg_part + (size_t)layer * GB * 256;
  const int per = (GB + 7) / 8;
  int b0 = chunk * per;
  int b1 = (b0 + per < GB) ? (b0 + per) : GB;
  float s0 = 0.f, s1 = 0.f, s2 = 0.f, s3 = 0.f;
  int b = b0;
  for (; b + 4 <= b1; b += 4) {
    s0 += base[(size_t)(b + 0) * 256 + c];
    s1 += base[(size_t)(b + 1) * 256 + c];
    s2 += base[(size_t)(b + 2) * 256 + c];
    s3 += base[(size_t)(b + 3) * 256 + c];
  }
  for (; b < b1; ++b) s0 += base[(size_t)b * 256 + c];
  atomicAdd(&hg[layer * 256 + c], (s0 + s1) + (s2 + s3));
}

extern "C" void kernel_launch(void* const* d_in, const int* in_sizes, int n_in,
                              void* d_out, int out_size, void* d_ws, size_t ws_size,
                              hipStream_t stream) {
  const float* feat = (const float*)d_in[0];
  const int* src    = (const int*)d_in[1];
  const int* dst    = (const int*)d_in[2];
  const float* W0   = (const float*)d_in[3];
  const float* b0   = (const float*)d_in[4];
  const float* W1   = (const float*)d_in[5];
  const float* b1   = (const float*)d_in[6];
  const float* pa   = (const float*)d_in[7];

  float* out_h = (float*)d_out;                      // [NN, DIM] f32
  float* hg    = out_h + (size_t)NN * DIM;           // [512] f32

  char* w = (char*)d_ws;
  int* cnt      = (int*)w;        w += (size_t)2 * NN * 4;      // [out_deg | in_deg]
  float* norm_s = (float*)w;      w += (size_t)NN * 4;
  float* norm_d = (float*)w;      w += (size_t)NN * 4;
  int* row_ptr  = (int*)w;        w += (size_t)(NN + 16) * 4;   // padded so colx is 16B-aligned
  int* cur      = (int*)w;        w += (size_t)NN * 4;          // atomic fill cursors
  int* colx     = (int*)w;        w += (size_t)(NE + 4) * 4;    // +4 pad for aligned int4 staging
  int* csum     = (int*)w;        w += 64 * 4;                  // scan chunk sums
  unsigned short* Wb0 = (unsigned short*)w;  w += (size_t)DIM * DIM * 2;
  unsigned short* Wb1 = (unsigned short*)w;  w += (size_t)DIM * DIM * 2;
  float* hg_part = (float*)w;     w += (size_t)2 * GB * 256 * 4;  // [2][GB][256] partial col sums
  uintptr_t ap = ((uintptr_t)w + 255) & ~(uintptr_t)255;
  unsigned short* featb = (unsigned short*)ap;                 // [NSLICE][NN][64] bf16 slice-major (reused as h1b)
  unsigned short* aggb  = featb + (size_t)NN * DIM;            // [NN,DIM] bf16, XOR-swizzled chunks

  const int agg_blocks = NSLICE * ((NN + NPB - 1) / NPB);

  zero_kernel<<<(2 * NN + 255) / 256, 256, 0, stream>>>(cnt, hg);
  deg_kernel<<<(NE / 4 + 255) / 256, 256, 0, stream>>>(src, dst, cnt);
  norm_kernel<<<SCB, 256, 0, stream>>>(cnt, norm_s, norm_d, csum);
  prep_kernel<<<12564, 256, 0, stream>>>(feat, norm_s, featb, W0, Wb0, W1, Wb1);
  scan_write_kernel<<<SCB, 256, 0, stream>>>(cnt, csum, row_ptr, cur);
  fill_kernel<<<(NE / 4 + 255) / 256, 256, 0, stream>>>(src, dst, cur, colx);

  // layer 1: only the scaled-bf16 h1 is live
  agg_kernel<<<agg_blocks, 256, 0, stream>>>(featb, aggb, row_ptr, colx, norm_d);
  gemm_mfma_kernel<<<GB, 256, 0, stream>>>(aggb, Wb0, b0, pa, norm_s,
                                           (float*)nullptr, featb, hg_part);

  // layer 2: f32 output only
  agg_kernel<<<agg_blocks, 256, 0, stream>>>(featb, aggb, row_ptr, colx, norm_d);
  gemm_mfma_kernel<<<GB, 256, 0, stream>>>(aggb, Wb1, b1, pa, norm_s,
                                           out_h, (unsigned short*)nullptr, hg_part + (size_t)GB * 256);

  // fold partials into hg (both layers)
  hg_reduce_kernel<<<16, 256, 0, stream>>>(hg_part, hg);
}

// Round 12
// 302.055 us; speedup vs baseline: 1.2553x; 1.2553x over previous
//
#include <hip/hip_runtime.h>
#include <stdint.h>

#define NN 50000
#define NE 800000
#define DIM 256

// hist privatization params
#define HB 128      // edge partitions (hist grid = 2*HB: src blocks + dst blocks)
#define HT 512      // hist threads/block
#define HALF 25000  // packed words (2 nodes/word, full 50K range) = 100KB LDS

// agg slice params: 4 channel-slices of 64 ch (128B rows = full cache line per gather).
#define NSLICE 4
#define SCH 64
#define NPB 64      // dst nodes per block (2 nodes per 8-lane group)
#define ECH 2048    // staged edges per LDS chunk (8 KB)

// gemm: 64-row tiles
#define GR 64
#define GB ((NN + GR - 1) / GR)   // 782

// scan: 49 chunks x 1024 nodes
#define SCB 49

typedef __bf16 bf16x8 __attribute__((ext_vector_type(8)));
typedef float f32x4 __attribute__((ext_vector_type(4)));
typedef float f32x2 __attribute__((ext_vector_type(2)));
typedef unsigned u32x4 __attribute__((ext_vector_type(4)));
typedef int i32x4 __attribute__((ext_vector_type(4)));

__device__ __forceinline__ unsigned short f2bf(float f) {
  union { float f; unsigned u; } v; v.f = f;
  unsigned r = v.u + 0x7fffu + ((v.u >> 16) & 1u);
  return (unsigned short)(r >> 16);
}

// async global->LDS 16B (wave-uniform LDS base + lane*16; global source per-lane)
__device__ __forceinline__ void gload_lds16(const void* g, void* l) {
  __builtin_amdgcn_global_load_lds(
      (const __attribute__((address_space(1))) unsigned*)g,
      (__attribute__((address_space(3))) unsigned*)l, 16, 0, 0);
}

// ---------------- LDS-privatized degree histograms: src+dst phases in PARALLEL blocks ----------------
__global__ __launch_bounds__(HT) void hist_kernel(const int* __restrict__ src,
                                                  const int* __restrict__ dst,
                                                  unsigned* __restrict__ Hs,
                                                  unsigned* __restrict__ Hd) {
  __shared__ unsigned lds[HALF];  // 100 KB — all 50K nodes, 16-bit packed counters
  const int tid = threadIdx.x;
  const int phase = blockIdx.x >> 7;   // 0: src, 1: dst
  const int b = blockIdx.x & (HB - 1); // edge partition (matches fill's partition)
  const int* arr = phase ? dst : src;
  unsigned* H = phase ? Hd : Hs;
  for (int w = tid; w < HALF; w += HT) lds[w] = 0u;
  __syncthreads();
  for (int e = b * HT + tid; e < NE; e += HB * HT) {
    unsigned n = (unsigned)arr[e];
    atomicAdd(&lds[n >> 1], 1u << ((n & 1) * 16));
  }
  __syncthreads();
  for (int w = tid; w < HALF; w += HT)
    H[(size_t)b * HALF + w] = lds[w];
}

// ---------------- reduce hists -> degrees+norms+Pd prefixes + hg zero + scan chunk sums ----------------
// block = 512 words = 1024 nodes; also emits csum[block] = sum of in-degrees (scan stage 1).
__global__ __launch_bounds__(512) void reduce_norm_kernel(const unsigned* __restrict__ Hs,
                                                          const unsigned* __restrict__ Hd,
                                                          unsigned* __restrict__ Pd,
                                                          int* __restrict__ in_cnt,
                                                          float* __restrict__ norm_s,
                                                          float* __restrict__ norm_d,
                                                          float* __restrict__ hg,
                                                          int* __restrict__ csum) {
  __shared__ int ws[8];
  const int tid = threadIdx.x;
  const int w = blockIdx.x * 512 + tid;
  if (blockIdx.x == 0) hg[tid] = 0.f;  // zero pooled output (512 floats)
  unsigned ss = 0, dd = 0;
  if (w < HALF) {
    for (int b = 0; b < HB; ++b) {
      Pd[(size_t)b * HALF + w] = dd;
      ss += Hs[(size_t)b * HALF + w];
      dd += Hd[(size_t)b * HALF + w];
    }
    int n0 = w * 2;
    unsigned s0 = ss & 0xffffu, s1 = ss >> 16;
    unsigned d0 = dd & 0xffffu, d1 = dd >> 16;
    in_cnt[n0] = (int)d0;
    in_cnt[n0 + 1] = (int)d1;
    norm_s[n0] = rsqrtf(fmaxf((float)s0, 1.0f));
    norm_s[n0 + 1] = rsqrtf(fmaxf((float)s1, 1.0f));
    norm_d[n0] = rsqrtf(fmaxf((float)d0, 1.0f));
    norm_d[n0 + 1] = rsqrtf(fmaxf((float)d1, 1.0f));
  }
  int deg = (int)((dd & 0xffffu) + (dd >> 16));
  int lane = tid & 63, wave = tid >> 6;
#pragma unroll
  for (int off = 32; off; off >>= 1) deg += __shfl_down(deg, off, 64);
  if (lane == 0) ws[wave] = deg;
  __syncthreads();
  if (tid == 0) {
    int s = 0;
#pragma unroll
    for (int i = 0; i < 8; ++i) s += ws[i];
    csum[blockIdx.x] = s;
  }
}

// ---------------- scan write: inline 49-entry chunk prefix (redundant per block) + node prefix ----------------
__global__ __launch_bounds__(256) void scan_write_kernel(const int* __restrict__ in_cnt,
                                                         const int* __restrict__ csum,
                                                         int* __restrict__ row_ptr) {
  __shared__ int wsum[4];
  int tid = threadIdx.x, lane = tid & 63, wave = tid >> 6;
  // chunk offsets: every thread scans csum[0..48] in-register
  int cv = (lane < SCB) ? csum[lane] : 0;
  int cincl = cv;
#pragma unroll
  for (int off = 1; off < 64; off <<= 1) {
    int t = __shfl_up(cincl, off, 64);
    if (lane >= off) cincl += t;
  }
  int myoff = __shfl(cincl, blockIdx.x, 64) - __shfl(cv, blockIdx.x, 64);
  int total = __shfl(cincl, SCB - 1, 64);
  if (blockIdx.x == 0 && tid == 0) row_ptr[NN] = total;

  int i0 = blockIdx.x * 1024 + tid * 4;
  int v[4];
#pragma unroll
  for (int j = 0; j < 4; ++j) {
    int i = i0 + j;
    v[j] = (i < NN) ? in_cnt[i] : 0;
  }
  int tsum = v[0] + v[1] + v[2] + v[3];
  int incl = tsum;
#pragma unroll
  for (int off = 1; off < 64; off <<= 1) {
    int t = __shfl_up(incl, off, 64);
    if (lane >= off) incl += t;
  }
  if (lane == 63) wsum[wave] = incl;
  __syncthreads();
  int woff = 0;
  for (int w = 0; w < wave; ++w) woff += wsum[w];
  int run = myoff + woff + (incl - tsum);
#pragma unroll
  for (int j = 0; j < 4; ++j) {
    int i = i0 + j;
    if (i < NN) row_ptr[i] = run;
    run += v[j];
  }
}

// ---------------- CSR fill, single pass (full-range 100KB LDS rank counters) ----------------
// Stores PRE-SCALED byte offsets: colx[..] = src*128 (128B slice-row byte offset).
__global__ __launch_bounds__(HT) void fill_kernel(const int* __restrict__ src,
                                                  const int* __restrict__ dst,
                                                  const int* __restrict__ row_ptr,
                                                  const unsigned* __restrict__ Pd,
                                                  int* __restrict__ colx) {
  __shared__ unsigned lds[HALF];  // 100 KB
  const int tid = threadIdx.x;
  const int b = blockIdx.x;
  for (int w = tid; w < HALF; w += HT) lds[w] = 0u;
  __syncthreads();
  for (int e = b * HT + tid; e < NE; e += HB * HT) {
    int n = dst[e];
    int sh = (n & 1) * 16;
    unsigned old = atomicAdd(&lds[n >> 1], 1u << sh);
    unsigned rank = (old >> sh) & 0xffffu;
    unsigned pref = (Pd[(size_t)b * HALF + (n >> 1)] >> sh) & 0xffffu;
    colx[row_ptr[n] + (int)pref + (int)rank] = src[e] << 7;  // ×128 B
  }
}

// ---------------- fused prep: cast feat (scaled by norm_s, SLICE-MAJOR 64ch) + swizzle W0/W1 ----------------
__device__ __forceinline__ void swizzleW_body(const float* __restrict__ W,
                                              unsigned short* __restrict__ Wb, int idx) {
  int lane = idx & 63;
  int blk = idx >> 6;
  int kc = blk & 7, nt = blk >> 3;
  int kbase = kc * 32 + (lane >> 4) * 8;
  int col = nt * 16 + (lane & 15);
  ushort4 o0, o1;
  o0.x = f2bf(W[(size_t)(kbase + 0) * DIM + col]);
  o0.y = f2bf(W[(size_t)(kbase + 1) * DIM + col]);
  o0.z = f2bf(W[(size_t)(kbase + 2) * DIM + col]);
  o0.w = f2bf(W[(size_t)(kbase + 3) * DIM + col]);
  o1.x = f2bf(W[(size_t)(kbase + 4) * DIM + col]);
  o1.y = f2bf(W[(size_t)(kbase + 5) * DIM + col]);
  o1.z = f2bf(W[(size_t)(kbase + 6) * DIM + col]);
  o1.w = f2bf(W[(size_t)(kbase + 7) * DIM + col]);
  ((ushort4*)Wb)[idx * 2 + 0] = o0;
  ((ushort4*)Wb)[idx * 2 + 1] = o1;
}

__global__ void prep_kernel(const float* __restrict__ feat, const float* __restrict__ norm_s,
                            unsigned short* __restrict__ featb,
                            const float* __restrict__ W0, unsigned short* __restrict__ Wb0,
                            const float* __restrict__ W1, unsigned short* __restrict__ Wb1) {
  int blk = blockIdx.x;
  if (blk < 12500) {
    int i = blk * 256 + threadIdx.x;  // float4 index over feat
    int node = i >> 6;
    int ch4 = i & 63;
    float s = norm_s[node];
    float4 v = ((const float4*)feat)[i];
    ushort4 o;
    o.x = f2bf(v.x * s); o.y = f2bf(v.y * s); o.z = f2bf(v.z * s); o.w = f2bf(v.w * s);
    int sl = ch4 >> 4;                // slice = ch/64
    int w4 = ch4 & 15;
    ((ushort4*)featb)[(size_t)sl * (NN * 16) + (size_t)node * 16 + w4] = o;
  } else if (blk < 12532) {
    swizzleW_body(W0, Wb0, (blk - 12500) * 256 + threadIdx.x);
  } else {
    swizzleW_body(W1, Wb1, (blk - 12532) * 256 + threadIdx.x);
  }
}

// ---------------- gather-aggregate, slice-major 128B rows + LDS-staged pre-scaled colx ----------------
// Latency x concurrency bound: 16-deep unroll (2x outstanding loads/wave); colx staging
// CACHED (re-read once per slice pass); NPB=64 amortizes staging barriers over 2x edges.
// Output aggb is XOR-SWIZZLED: 16B chunk column p -> p ^ ((node&7)<<4) (see gemm).
__device__ __forceinline__ void acc_row(f32x2* a, u32x4 p) {
  f32x2 v0 = { __uint_as_float(p.x << 16), __uint_as_float(p.x & 0xffff0000u) };
  a[0] += v0;
  f32x2 v1 = { __uint_as_float(p.y << 16), __uint_as_float(p.y & 0xffff0000u) };
  a[1] += v1;
  f32x2 v2 = { __uint_as_float(p.z << 16), __uint_as_float(p.z & 0xffff0000u) };
  a[2] += v2;
  f32x2 v3 = { __uint_as_float(p.w << 16), __uint_as_float(p.w & 0xffff0000u) };
  a[3] += v3;
}

__global__ __launch_bounds__(256) void agg_kernel(const unsigned short* __restrict__ X,
                                                  unsigned short* __restrict__ agg,
                                                  const int* __restrict__ row_ptr,
                                                  const int* __restrict__ colx,
                                                  const float* __restrict__ norm_d) {
  __shared__ int ecol[ECH];
  const int s = blockIdx.x & (NSLICE - 1);
  const int nb = blockIdx.x >> 2;
  const int tid = threadIdx.x;
  const int grp = tid >> 3;                  // 0..31: 8-lane groups; each owns 2 nodes
  const int cl = tid & 7;                    // 16B sub-chunk of the 128B row

  const int nfirst = nb * NPB;
  const int nlast = (nfirst + NPB < NN) ? (nfirst + NPB) : NN;
  const int estart = row_ptr[nfirst];
  const int eend = row_ptr[nlast];

  const char* Xp = (const char*)(X + (size_t)s * (NN * SCH));
  const int lsub = cl * 16;

  int nodes[2];
  nodes[0] = nfirst + grp;
  nodes[1] = nfirst + 32 + grp;

  f32x2 acc2[2][4];
#pragma unroll
  for (int q = 0; q < 2; ++q)
#pragma unroll
    for (int j = 0; j < 4; ++j) acc2[q][j] = (f32x2){0.f, 0.f};

  int e_[2], end_[2];
#pragma unroll
  for (int q = 0; q < 2; ++q) {
    if (nodes[q] < NN) { e_[q] = row_ptr[nodes[q]]; end_[q] = row_ptr[nodes[q] + 1]; }
    else { e_[q] = 0; end_[q] = 0; }
  }

  const int base0 = estart & ~3;
  for (int base = base0; base < eend; base += ECH) {
    const int lim = (base + ECH < eend) ? (base + ECH) : eend;
    __syncthreads();
    for (int k = base + tid * 4; k < lim; k += 1024) {
      i32x4 v = *(const i32x4*)(colx + k);
      *(i32x4*)&ecol[k - base] = v;
    }
    __syncthreads();
#pragma unroll
    for (int q = 0; q < 2; ++q) {
      int e = e_[q];
      const int hi = (end_[q] < lim) ? end_[q] : lim;
      f32x2* a = acc2[q];
      for (; e + 16 <= hi; e += 16) {
        int o_[16];
#pragma unroll
        for (int j = 0; j < 16; ++j) o_[j] = ecol[e - base + j];
        u32x4 r_[16];
#pragma unroll
        for (int j = 0; j < 16; ++j)
          r_[j] = *(const u32x4*)(Xp + (size_t)(unsigned)(o_[j] | lsub));
#pragma unroll
        for (int j = 0; j < 16; ++j) acc_row(a, r_[j]);
      }
      if (e + 8 <= hi) {
        int o_[8];
#pragma unroll
        for (int j = 0; j < 8; ++j) o_[j] = ecol[e - base + j];
        u32x4 r_[8];
#pragma unroll
        for (int j = 0; j < 8; ++j)
          r_[j] = *(const u32x4*)(Xp + (size_t)(unsigned)(o_[j] | lsub));
#pragma unroll
        for (int j = 0; j < 8; ++j) acc_row(a, r_[j]);
        e += 8;
      }
      if (e + 4 <= hi) {
        int o_[4];
#pragma unroll
        for (int j = 0; j < 4; ++j) o_[j] = ecol[e - base + j];
        u32x4 r_[4];
#pragma unroll
        for (int j = 0; j < 4; ++j)
          r_[j] = *(const u32x4*)(Xp + (size_t)(unsigned)(o_[j] | lsub));
#pragma unroll
        for (int j = 0; j < 4; ++j) acc_row(a, r_[j]);
        e += 4;
      }
      for (; e < hi; ++e) {
        int o0 = ecol[e - base];
        u32x4 r = *(const u32x4*)(Xp + (size_t)(unsigned)(o0 | lsub));
        acc_row(a, r);
      }
      e_[q] = e;
    }
  }

#pragma unroll
  for (int q = 0; q < 2; ++q) {
    int node = nodes[q];
    if (node < NN) {
      float nd = norm_d[node];
      f32x2* a = acc2[q];
      u32x4 o;
      o.x = (unsigned)f2bf(a[0].x * nd) | ((unsigned)f2bf(a[0].y * nd) << 16);
      o.y = (unsigned)f2bf(a[1].x * nd) | ((unsigned)f2bf(a[1].y * nd) << 16);
      o.z = (unsigned)f2bf(a[2].x * nd) | ((unsigned)f2bf(a[2].y * nd) << 16);
      o.w = (unsigned)f2bf(a[3].x * nd) | ((unsigned)f2bf(a[3].y * nd) << 16);
      // swizzled store: chunk col p ^ ((node&7)<<4); contiguous 128B per group
      unsigned pcol = (unsigned)(s * 128 + cl * 16) ^ (((unsigned)node & 7u) << 4);
      __builtin_nontemporal_store(o, (u32x4*)((char*)agg + (size_t)node * 512 + pcol));
    }
  }
}

// ---------------- MFMA GEMM (64-row tile): global_load_lds linear staging + XOR ds_read ----------------
// A (=aggb) is byte-swizzled by agg; staging is a pure linear 32KB copy via
// global_load_lds width=16; ds_read applies c ^= (row&7)<<4 to recover canonical chunks.
// Pooling: contention-free per-block column partials to hg_part.
// Exactly one of C (f32, canonical row-major) / Cb (bf16, canonical SLICE-MAJOR 64ch) non-null.
#define FROW 260     // f32 row stride for epilogue staging
__global__ __launch_bounds__(256) void gemm_mfma_kernel(const unsigned short* __restrict__ A,
                                                        const unsigned short* __restrict__ Wb,
                                                        const float* __restrict__ bias,
                                                        const float* __restrict__ prelu_a_ptr,
                                                        const float* __restrict__ norm_s,
                                                        float* __restrict__ C,
                                                        unsigned short* __restrict__ Cb,
                                                        float* __restrict__ hg_part) {
  __shared__ __attribute__((aligned(16))) char Asb[GR * 512];  // 32768 B, linear; reused as LF
  int tid = threadIdx.x;
  int r0 = blockIdx.x * GR;
  const char* Ab = (const char*)A;
#pragma unroll
  for (int p = 0; p < 8; ++p) {
    int off = p * 4096 + tid * 16;
    int row = off >> 9;
    int col = off & 511;
    int grow = r0 + row;
    if (grow > NN - 1) grow = NN - 1;  // clamp: OOB rows read row NN-1 (outputs masked)
    gload_lds16(Ab + (size_t)grow * 512 + col, Asb + off);
  }
  __syncthreads();

  int wave = tid >> 6, lane = tid & 63;
  int quad = lane >> 4, l16 = lane & 15;

  f32x4 acc[4][4];
#pragma unroll
  for (int mt = 0; mt < 4; ++mt)
#pragma unroll
    for (int nti = 0; nti < 4; ++nti)
      acc[mt][nti] = (f32x4){0.f, 0.f, 0.f, 0.f};

#pragma unroll
  for (int kc = 0; kc < 8; ++kc) {
    bf16x8 a[4], b[4];
#pragma unroll
    for (int mt = 0; mt < 4; ++mt) {
      int row = mt * 16 + l16;
      int c = (kc * 64 + quad * 16) ^ ((row & 7) << 4);
      a[mt] = *(const bf16x8*)(Asb + row * 512 + c);
    }
#pragma unroll
    for (int nti = 0; nti < 4; ++nti) {
      int nt = wave * 4 + nti;
      b[nti] = *(const bf16x8*)(Wb + ((size_t)(nt * 8 + kc) * 64 + lane) * 8);
    }
#pragma unroll
    for (int mt = 0; mt < 4; ++mt)
#pragma unroll
      for (int nti = 0; nti < 4; ++nti)
        acc[mt][nti] = __builtin_amdgcn_mfma_f32_16x16x32_bf16(a[mt], b[nti], acc[mt][nti], 0, 0, 0);
  }

  // bias + PReLU + column sums in registers (C-layout: col=l16, row=mt*16+quad*4+r)
  float pa = *prelu_a_ptr;
  float bv[4], cs[4];
#pragma unroll
  for (int nti = 0; nti < 4; ++nti) {
    bv[nti] = bias[wave * 64 + nti * 16 + l16];
    cs[nti] = 0.f;
  }
#pragma unroll
  for (int mt = 0; mt < 4; ++mt) {
#pragma unroll
    for (int nti = 0; nti < 4; ++nti) {
#pragma unroll
      for (int r = 0; r < 4; ++r) {
        int rowg = r0 + mt * 16 + quad * 4 + r;
        float x = acc[mt][nti][r] + bv[nti];
        x = (x >= 0.f) ? x : pa * x;
        acc[mt][nti][r] = x;
        if (rowg < NN) cs[nti] += x;
      }
    }
  }
#pragma unroll
  for (int nti = 0; nti < 4; ++nti) {
    cs[nti] += __shfl_xor(cs[nti], 16, 64);
    cs[nti] += __shfl_xor(cs[nti], 32, 64);
  }
  if (quad == 0) {
#pragma unroll
    for (int nti = 0; nti < 4; ++nti)
      hg_part[(size_t)blockIdx.x * 256 + wave * 64 + nti * 16 + l16] = cs[nti];
  }

  // coalesced store epilogue: stage 16-row chunks through LDS
  float* LF = (float*)Asb;  // [16][FROW] = 16640 B < 32768 B
#pragma unroll
  for (int chunk = 0; chunk < 4; ++chunk) {
    __syncthreads();
#pragma unroll
    for (int nti = 0; nti < 4; ++nti) {
      int colw = wave * 64 + nti * 16 + l16;
#pragma unroll
      for (int r = 0; r < 4; ++r)
        LF[(quad * 4 + r) * FROW + colw] = acc[chunk][nti][r];
    }
    __syncthreads();
    int rowbase = r0 + chunk * 16;
    if (C) {
#pragma unroll
      for (int s = 0; s < 4; ++s) {
        int g = s * 256 + tid;
        int row = g >> 6, cg = g & 63;
        int rowg = rowbase + row;
        if (rowg < NN) {
          float4 v = *(const float4*)&LF[row * FROW + cg * 4];
          *(float4*)(C + (size_t)rowg * DIM + cg * 4) = v;
        }
      }
    }
    if (Cb) {
#pragma unroll
      for (int s = 0; s < 2; ++s) {
        int g = s * 256 + tid;
        int row = g >> 5, cg = g & 31;    // cg: 8-channel group (0..31)
        int rowg = rowbase + row;
        if (rowg < NN) {
          float ns = norm_s[rowg];
          float4 v0 = *(const float4*)&LF[row * FROW + cg * 8];
          float4 v1 = *(const float4*)&LF[row * FROW + cg * 8 + 4];
          uint4 o;
          o.x = (unsigned)f2bf(v0.x * ns) | ((unsigned)f2bf(v0.y * ns) << 16);
          o.y = (unsigned)f2bf(v0.z * ns) | ((unsigned)f2bf(v0.w * ns) << 16);
          o.z = (unsigned)f2bf(v1.x * ns) | ((unsigned)f2bf(v1.y * ns) << 16);
          o.w = (unsigned)f2bf(v1.z * ns) | ((unsigned)f2bf(v1.w * ns) << 16);
          // canonical slice-major store: slice = cg>>3, 8ch-group within slice = cg&7
          unsigned short* outp = Cb + (size_t)(cg >> 3) * (NN * SCH)
                               + (size_t)rowg * SCH + (size_t)(cg & 7) * 8;
          *(uint4*)outp = o;
        }
      }
    }
  }
}

// ---------------- pooled-output reduction: hg[layer][c] = sum_b hg_part[layer][b][c] ----------------
__global__ __launch_bounds__(256) void hg_reduce_kernel(const float* __restrict__ hg_part,
                                                        float* __restrict__ hg) {
  const int layer = blockIdx.x >> 3;
  const int chunk = blockIdx.x & 7;
  const int c = threadIdx.x;
  const float* base = hg_part + (size_t)layer * GB * 256;
  const int per = (GB + 7) / 8;
  int b0 = chunk * per;
  int b1 = (b0 + per < GB) ? (b0 + per) : GB;
  float s0 = 0.f, s1 = 0.f, s2 = 0.f, s3 = 0.f;
  int b = b0;
  for (; b + 4 <= b1; b += 4) {
    s0 += base[(size_t)(b + 0) * 256 + c];
    s1 += base[(size_t)(b + 1) * 256 + c];
    s2 += base[(size_t)(b + 2) * 256 + c];
    s3 += base[(size_t)(b + 3) * 256 + c];
  }
  for (; b < b1; ++b) s0 += base[(size_t)b * 256 + c];
  atomicAdd(&hg[layer * 256 + c], (s0 + s1) + (s2 + s3));
}

extern "C" void kernel_launch(void* const* d_in, const int* in_sizes, int n_in,
                              void* d_out, int out_size, void* d_ws, size_t ws_size,
                              hipStream_t stream) {
  const float* feat = (const float*)d_in[0];
  const int* src    = (const int*)d_in[1];
  const int* dst    = (const int*)d_in[2];
  const float* W0   = (const float*)d_in[3];
  const float* b0   = (const float*)d_in[4];
  const float* W1   = (const float*)d_in[5];
  const float* b1   = (const float*)d_in[6];
  const float* pa   = (const float*)d_in[7];

  float* out_h = (float*)d_out;                      // [NN, DIM] f32
  float* hg    = out_h + (size_t)NN * DIM;           // [512] f32

  char* w = (char*)d_ws;
  int* in_cnt   = (int*)w;        w += (size_t)NN * 4;
  float* norm_s = (float*)w;      w += (size_t)NN * 4;
  float* norm_d = (float*)w;      w += (size_t)NN * 4;
  int* row_ptr  = (int*)w;        w += (size_t)(NN + 16) * 4;   // padded so colx is 16B-aligned
  int* colx     = (int*)w;        w += (size_t)(NE + 4) * 4;    // +4 pad for aligned int4 staging
  int* csum     = (int*)w;        w += 64 * 4;                  // scan chunk sums
  unsigned short* Wb0 = (unsigned short*)w;  w += (size_t)DIM * DIM * 2;
  unsigned short* Wb1 = (unsigned short*)w;  w += (size_t)DIM * DIM * 2;
  float* hg_part = (float*)w;     w += (size_t)2 * GB * 256 * 4;  // [2][GB][256] partial col sums
  uintptr_t ap = ((uintptr_t)w + 255) & ~(uintptr_t)255;
  unsigned short* featb = (unsigned short*)ap;                 // [NSLICE][NN][64] bf16 slice-major (reused as h1b)
  unsigned short* aggb  = featb + (size_t)NN * DIM;            // [NN,DIM] bf16, XOR-swizzled chunks
  // aliases (dead before their region's first real use):
  unsigned* Hs = (unsigned*)featb;               // [HB][25000 words] = 12.8 MB
  unsigned* Hd = Hs + (size_t)HB * HALF;         // [HB][25000 words] = 12.8 MB
  unsigned* Pd = (unsigned*)aggb;                // [HB][25000 words] = 12.8 MB (dead after fill)

  const int agg_blocks = NSLICE * ((NN + NPB - 1) / NPB);

  hist_kernel<<<2 * HB, HT, 0, stream>>>(src, dst, Hs, Hd);
  reduce_norm_kernel<<<SCB, 512, 0, stream>>>(Hs, Hd, Pd, in_cnt, norm_s, norm_d, hg, csum);
  prep_kernel<<<12564, 256, 0, stream>>>(feat, norm_s, featb, W0, Wb0, W1, Wb1);
  scan_write_kernel<<<SCB, 256, 0, stream>>>(in_cnt, csum, row_ptr);
  fill_kernel<<<HB, HT, 0, stream>>>(src, dst, row_ptr, Pd, colx);

  // layer 1: only the scaled-bf16 h1 is live
  agg_kernel<<<agg_blocks, 256, 0, stream>>>(featb, aggb, row_ptr, colx, norm_d);
  gemm_mfma_kernel<<<GB, 256, 0, stream>>>(aggb, Wb0, b0, pa, norm_s,
                                           (float*)nullptr, featb, hg_part);

  // layer 2: f32 output only
  agg_kernel<<<agg_blocks, 256, 0, stream>>>(featb, aggb, row_ptr, colx, norm_d);
  gemm_mfma_kernel<<<GB, 256, 0, stream>>>(aggb, Wb1, b1, pa, norm_s,
                                           out_h, (unsigned short*)nullptr, hg_part + (size_t)GB * 256);

  // fold partials into hg (both layers)
  hg_reduce_kernel<<<16, 256, 0, stream>>>(hg_part, hg);
}